// Round 8
// baseline (97.346 us; speedup 1.0000x reference)
//
#include <hip/hip_runtime.h>

// Problem sizes (fixed by the reference)
#define BDIM 8
#define QDIM 1024
#define KDIM 1024
#define HDIM 64   // = DQ = DK = DV

constexpr float kLog2e = 1.4426950408889634f;
constexpr float kC2 = 2.0f * kLog2e;

// ---------------------------------------------------------------------------
// K1: both projections; emits Eq/Ek = min(exp2(kC2 * (X@W)), 2^15).
// Clamp keeps the quad-rational denominators finite (u<=2^30+1, d01*d23<=2^121)
// with tanh error < 2^-25 (only in the already-saturated rail).
// ---------------------------------------------------------------------------
__global__ __launch_bounds__(256) void proj_both(
    const float* __restrict__ queries, const float* __restrict__ keys,
    const float* __restrict__ Wq, const float* __restrict__ Wk,
    float* __restrict__ eq, float* __restrict__ ek) {
  const int bid = blockIdx.x;
  const bool isK = bid >= 128;
  const float* X = isK ? keys : queries;
  const float* W = isK ? Wk : Wq;
  float* Y = isK ? ek : eq;
  const long long base = (long long)(bid & 127) * 64 * 64;

  __shared__ __align__(16) float xs[64][68];
  __shared__ __align__(16) float ws[64][64];
  const int t = threadIdx.x;
  {
    const int r = t >> 4, sl = t & 15;
#pragma unroll
    for (int i = 0; i < 4; ++i) {
      *(float4*)&xs[r + i * 16][sl * 4] =
          *(const float4*)&X[base + (long long)(r + i * 16) * 64 + sl * 4];
      *(float4*)&ws[r + i * 16][sl * 4] =
          *(const float4*)&W[(r + i * 16) * 64 + sl * 4];
    }
  }
  __syncthreads();

  const int r = t >> 2;
  const int c0 = (t & 3) * 16;
  float acc[16];
#pragma unroll
  for (int j = 0; j < 16; ++j) acc[j] = 0.0f;

#pragma unroll 8
  for (int d = 0; d < 64; ++d) {
    const float xv = xs[r][d];
#pragma unroll
    for (int j4 = 0; j4 < 4; ++j4) {
      float4 w4 = *(float4*)&ws[d][c0 + j4 * 4];
      acc[j4 * 4 + 0] = fmaf(xv, w4.x, acc[j4 * 4 + 0]);
      acc[j4 * 4 + 1] = fmaf(xv, w4.y, acc[j4 * 4 + 1]);
      acc[j4 * 4 + 2] = fmaf(xv, w4.z, acc[j4 * 4 + 2]);
      acc[j4 * 4 + 3] = fmaf(xv, w4.w, acc[j4 * 4 + 3]);
    }
  }
#pragma unroll
  for (int j4 = 0; j4 < 4; ++j4) {
    float4 o = make_float4(
        fminf(__builtin_amdgcn_exp2f(acc[j4 * 4 + 0] * kC2), 32768.0f),
        fminf(__builtin_amdgcn_exp2f(acc[j4 * 4 + 1] * kC2), 32768.0f),
        fminf(__builtin_amdgcn_exp2f(acc[j4 * 4 + 2] * kC2), 32768.0f),
        fminf(__builtin_amdgcn_exp2f(acc[j4 * 4 + 3] * kC2), 32768.0f));
    *(float4*)&Y[base + (long long)r * 64 + c0 + j4 * 4] = o;
  }
}

// ---------------------------------------------------------------------------
// K2: fused scores + online softmax + PV, flash-style over the FULL k range
// per block (no chunk split, no partials, no combine, no 32MB scores buffer).
// Block = 8 q-rows x 64 k-tile, 256 threads. Thread (tq=t>>5, lane=t&31):
// scores for k = {2*lane, 2*lane+1}, PV accumulator for d = {2*lane, 2*lane+1}.
// Grid = 1024 blocks (b = g&7 for load balance) -> 4 blocks/CU, 4 waves/SIMD.
// Scores math: quad rational (4 h-terms per rcp), round-3 reg double-buffer.
// ---------------------------------------------------------------------------
__global__ __launch_bounds__(256, 4) void fused_kernel(
    const float* __restrict__ eqp, const float* __restrict__ ekp,
    const float* __restrict__ vglob, const float* __restrict__ wv,
    const int* __restrict__ vlens, float* __restrict__ out) {
  const int g = blockIdx.x;
  const int b = g & 7;          // all batches start immediately (balance)
  const int q0 = (g >> 3) * 8;  // 128 q-tiles per b
  const int vlen = vlens[b];
  const int ntiles = (vlen + 63) >> 6;

  __shared__ __align__(16) float qs[8][68];
  __shared__ __align__(16) float ks[64][64];  // XOR-swizzled Ek tile
  __shared__ __align__(16) float vs[64][64];  // V tile (linear)
  __shared__ __align__(16) float ps[8][68];   // attn weights
  const int t = threadIdx.x;
  const int tq = t >> 5;           // q row 0..7
  const int lane = t & 31;
  const int kb0 = lane * 2;        // this thread's 2 k columns
  const int kb1 = kb0 + 1;
  const int key0 = (kb0 ^ (kb0 >> 2)) & 15;
  const int key1 = (kb1 ^ (kb1 >> 2)) & 15;
  const int d2 = lane * 2;         // this thread's 2 d columns

  float sumw = 0.0f;
#pragma unroll
  for (int h = 0; h < 64; ++h) sumw += wv[h];  // uniform -> scalar loads

  {  // Q rows for this block (8x64 floats = 128 float4)
    if (t < 128) {
      const int r = t >> 4, sl = t & 15;
      *(float4*)&qs[r][sl * 4] =
          *(const float4*)&eqp[(long long)(b * QDIM + q0 + r) * 64 + sl * 4];
    }
  }

  float2 o2 = make_float2(0.0f, 0.0f);
  float m = -3.0e38f, l = 0.0f;

  for (int kt = 0; kt < ntiles; ++kt) {
    __syncthreads();  // prev PV done reading vs/ps
    // stage Ek (swizzled) + V (linear): 4 float4 each per thread
#pragma unroll
    for (int i = 0; i < 4; ++i) {
      const int f = i * 256 + t;
      const int k = f >> 4, sl = f & 15;
      const int key = (k ^ (k >> 2)) & 15;
      const long long grow = (long long)(b * KDIM + kt * 64 + k) * 64 + sl * 4;
      *(float4*)&ks[k][(sl ^ key) * 4] = *(const float4*)&ekp[grow];
      *(float4*)&vs[k][sl * 4] = *(const float4*)&vglob[grow];
    }
    __syncthreads();

    // ---- scores for (tq, kb0/kb1): reg double-buffered h-pipeline ----
    float acc0 = 0.0f, acc1 = 0.0f;
    float4 qA, kA0, kA1;
    float4 qB, kB0, kB1;

#define LOAD_STAGE(QF, K0, K1, H)                          \
  QF = *(const float4*)&qs[tq][(H) * 4];                   \
  K0 = *(const float4*)&ks[kb0][((H) ^ key0) * 4];         \
  K1 = *(const float4*)&ks[kb1][((H) ^ key1) * 4];

// quad rational: acc += (n01*d23 + n23*d01) * rcp(d01*d23), ui = 1+Eq*Ek
#define QUAD(ACC, QF, KF, W0, W1, W2, W3)                  \
  {                                                        \
    const float u0 = fmaf(QF.x, KF.x, 1.0f);               \
    const float u1 = fmaf(QF.y, KF.y, 1.0f);               \
    const float u2 = fmaf(QF.z, KF.z, 1.0f);               \
    const float u3 = fmaf(QF.w, KF.w, 1.0f);               \
    const float d01 = u0 * u1;                             \
    const float d23 = u2 * u3;                             \
    const float n01 = fmaf(W1, u0, W0 * u1);               \
    const float n23 = fmaf(W3, u2, W2 * u3);               \
    const float num = fmaf(n23, d01, n01 * d23);           \
    ACC = fmaf(num, __builtin_amdgcn_rcpf(d01 * d23), ACC);\
  }

#define COMP_STAGE(QF, K0, K1, H)                          \
  {                                                        \
    const float w0 = wv[(H) * 4 + 0];                      \
    const float w1 = wv[(H) * 4 + 1];                      \
    const float w2 = wv[(H) * 4 + 2];                      \
    const float w3 = wv[(H) * 4 + 3];                      \
    QUAD(acc0, QF, K0, w0, w1, w2, w3)                     \
    QUAD(acc1, QF, K1, w0, w1, w2, w3)                     \
  }

    LOAD_STAGE(qA, kA0, kA1, 0)
#pragma unroll
    for (int h = 0; h < 16; h += 2) {
      LOAD_STAGE(qB, kB0, kB1, h + 1)
      COMP_STAGE(qA, kA0, kA1, h)
      if (h + 2 < 16) LOAD_STAGE(qA, kA0, kA1, h + 2)
      COMP_STAGE(qB, kB0, kB1, h + 1)
    }
#undef LOAD_STAGE
#undef COMP_STAGE
#undef QUAD

    // ---- mask + online softmax (row = 32 lanes, in-wave) ----
    const int kg0 = kt * 64 + kb0;
    float s0 = fmaf(-2.0f, acc0, sumw);
    float s1 = fmaf(-2.0f, acc1, sumw);
    s0 = (kg0 + 0 < vlen) ? s0 : -3.0e38f;
    s1 = (kg0 + 1 < vlen) ? s1 : -3.0e38f;
    float tm = fmaxf(s0, s1);
#pragma unroll
    for (int s = 1; s < 32; s <<= 1) tm = fmaxf(tm, __shfl_xor(tm, s, 64));
    const float mn = fmaxf(m, tm);
    const float scale = __builtin_amdgcn_exp2f((m - mn) * kLog2e);
    const float p0 = __builtin_amdgcn_exp2f((s0 - mn) * kLog2e);
    const float p1 = __builtin_amdgcn_exp2f((s1 - mn) * kLog2e);
    float tsum = p0 + p1;
#pragma unroll
    for (int s = 1; s < 32; s <<= 1) tsum += __shfl_xor(tsum, s, 64);
    l = fmaf(l, scale, tsum);
    m = mn;
    o2.x *= scale;
    o2.y *= scale;
    *(float2*)&ps[tq][kb0] = make_float2(p0, p1);
    __syncthreads();

    // ---- PV: o2 += sum_k ps[tq][k] * vs[k][d2..d2+1] ----
#pragma unroll 4
    for (int k4 = 0; k4 < 16; ++k4) {
      const float4 p4 = *(const float4*)&ps[tq][k4 * 4];
      const float pw[4] = {p4.x, p4.y, p4.z, p4.w};
#pragma unroll
      for (int e = 0; e < 4; ++e) {
        const float2 vv = *(const float2*)&vs[k4 * 4 + e][d2];
        o2.x = fmaf(pw[e], vv.x, o2.x);
        o2.y = fmaf(pw[e], vv.y, o2.y);
      }
    }
  }

  const float inv = __builtin_amdgcn_rcpf(l);
  *(float2*)&out[(long long)(b * QDIM + q0 + tq) * 64 + d2] =
      make_float2(o2.x * inv, o2.y * inv);
}

// ---------------------------------------------------------------------------
extern "C" void kernel_launch(void* const* d_in, const int* in_sizes, int n_in,
                              void* d_out, int out_size, void* d_ws, size_t ws_size,
                              hipStream_t stream) {
  const float* queries = (const float*)d_in[0];
  const float* keys    = (const float*)d_in[1];
  const float* values  = (const float*)d_in[2];
  const int*   vlens   = (const int*)d_in[3];
  const float* Wq      = (const float*)d_in[4];
  const float* Wk      = (const float*)d_in[5];
  const float* wv      = (const float*)d_in[6];
  float* out = (float*)d_out;

  float* eq = (float*)d_ws;                     // B*Q*H = 2 MB
  float* ek = eq + (size_t)BDIM * QDIM * HDIM;  // B*K*H = 2 MB

  proj_both<<<dim3(256), 256, 0, stream>>>(queries, keys, Wq, Wk, eq, ek);
  fused_kernel<<<dim3(1024), 256, 0, stream>>>(eq, ek, values, wv, vlens, out);
}

// Round 9
// 70.143 us; speedup vs baseline: 1.3878x; 1.3878x over previous
//
#include <hip/hip_runtime.h>

// Problem sizes (fixed by the reference)
#define BDIM 8
#define QDIM 1024
#define KDIM 1024
#define HDIM 64   // = DQ = DK = DV

constexpr float kLog2e = 1.4426950408889634f;
constexpr float kC2 = 2.0f * kLog2e;

// ---------------------------------------------------------------------------
// K1: both projections; emits Eq/Ek = min(exp2(kC2 * (X@W)), 2^15).
// Clamp keeps quad-rational denominators finite; tanh error < 2^-25.
// ---------------------------------------------------------------------------
__global__ __launch_bounds__(256) void proj_both(
    const float* __restrict__ queries, const float* __restrict__ keys,
    const float* __restrict__ Wq, const float* __restrict__ Wk,
    float* __restrict__ eq, float* __restrict__ ek) {
  const int bid = blockIdx.x;
  const bool isK = bid >= 128;
  const float* X = isK ? keys : queries;
  const float* W = isK ? Wk : Wq;
  float* Y = isK ? ek : eq;
  const long long base = (long long)(bid & 127) * 64 * 64;

  __shared__ __align__(16) float xs[64][68];
  __shared__ __align__(16) float ws[64][64];
  const int t = threadIdx.x;
  {
    const int r = t >> 4, sl = t & 15;
#pragma unroll
    for (int i = 0; i < 4; ++i) {
      *(float4*)&xs[r + i * 16][sl * 4] =
          *(const float4*)&X[base + (long long)(r + i * 16) * 64 + sl * 4];
      *(float4*)&ws[r + i * 16][sl * 4] =
          *(const float4*)&W[(r + i * 16) * 64 + sl * 4];
    }
  }
  __syncthreads();

  const int r = t >> 2;
  const int c0 = (t & 3) * 16;
  float acc[16];
#pragma unroll
  for (int j = 0; j < 16; ++j) acc[j] = 0.0f;

#pragma unroll 8
  for (int d = 0; d < 64; ++d) {
    const float xv = xs[r][d];
#pragma unroll
    for (int j4 = 0; j4 < 4; ++j4) {
      float4 w4 = *(float4*)&ws[d][c0 + j4 * 4];
      acc[j4 * 4 + 0] = fmaf(xv, w4.x, acc[j4 * 4 + 0]);
      acc[j4 * 4 + 1] = fmaf(xv, w4.y, acc[j4 * 4 + 1]);
      acc[j4 * 4 + 2] = fmaf(xv, w4.z, acc[j4 * 4 + 2]);
      acc[j4 * 4 + 3] = fmaf(xv, w4.w, acc[j4 * 4 + 3]);
    }
  }
#pragma unroll
  for (int j4 = 0; j4 < 4; ++j4) {
    float4 o = make_float4(
        fminf(__builtin_amdgcn_exp2f(acc[j4 * 4 + 0] * kC2), 32768.0f),
        fminf(__builtin_amdgcn_exp2f(acc[j4 * 4 + 1] * kC2), 32768.0f),
        fminf(__builtin_amdgcn_exp2f(acc[j4 * 4 + 2] * kC2), 32768.0f),
        fminf(__builtin_amdgcn_exp2f(acc[j4 * 4 + 3] * kC2), 32768.0f));
    *(float4*)&Y[base + (long long)r * 64 + c0 + j4 * 4] = o;
  }
}

// ---------------------------------------------------------------------------
// K2: fused scores + online softmax + PV, flash-style, full K per block.
// Block = 8 q-rows, 128 threads: (tq = t>>4, kg = t&15). Wave = 4 rows x
// 16 kg -> EXACTLY round-3's measured-conflict-free swizzle read pattern,
// 4 independent quad-rational chains per thread.
// Grid = 1024 items (b, qtile8), LPT-ordered: batches sorted by descending
// vlen via a uniform compare-exchange network (longest blocks dispatch
// first; short ones backfill the tail -> balanced makespan).
// ---------------------------------------------------------------------------
__global__ __launch_bounds__(128, 2) void fused_kernel(
    const float* __restrict__ eqp, const float* __restrict__ ekp,
    const float* __restrict__ vglob, const float* __restrict__ wv,
    const int* __restrict__ vlens, float* __restrict__ out) {
  // ---- uniform LPT mapping: sort packed keys (vlen<<3)|b descending ----
  int k0 = (vlens[0] << 3) | 0, k1 = (vlens[1] << 3) | 1;
  int k2 = (vlens[2] << 3) | 2, k3 = (vlens[3] << 3) | 3;
  int k4 = (vlens[4] << 3) | 4, k5 = (vlens[5] << 3) | 5;
  int k6 = (vlens[6] << 3) | 6, k7 = (vlens[7] << 3) | 7;
#define CE(a, b) { const int lo = min(a, b), hi = max(a, b); a = hi; b = lo; }
  // Batcher odd-even merge sort for 8 (desc)
  CE(k0, k1) CE(k2, k3) CE(k4, k5) CE(k6, k7)
  CE(k0, k2) CE(k1, k3) CE(k4, k6) CE(k5, k7)
  CE(k1, k2) CE(k5, k6)
  CE(k0, k4) CE(k1, k5) CE(k2, k6) CE(k3, k7)
  CE(k2, k4) CE(k3, k5)
  CE(k1, k2) CE(k3, k4) CE(k5, k6)
#undef CE
  const int g = blockIdx.x;
  const int rank = g >> 7;  // 128 q-tiles per batch
  int kk = k0;
  kk = (rank == 1) ? k1 : kk; kk = (rank == 2) ? k2 : kk;
  kk = (rank == 3) ? k3 : kk; kk = (rank == 4) ? k4 : kk;
  kk = (rank == 5) ? k5 : kk; kk = (rank == 6) ? k6 : kk;
  kk = (rank == 7) ? k7 : kk;
  const int b = kk & 7;
  const int vlen = kk >> 3;
  const int q0 = (g & 127) * 8;
  const int ntiles = (vlen + 63) >> 6;

  __shared__ __align__(16) float qs[8][64];   // broadcast reads: no pad needed
  __shared__ __align__(16) float ks[64][64];  // XOR-swizzled Ek tile
  __shared__ __align__(16) float vs[64][64];  // V tile (linear)
  __shared__ __align__(16) float ps[8][68];   // attn weights
  const int t = threadIdx.x;
  const int tq = t >> 4;           // q row 0..7
  const int kg = t & 15;           // k group / d group
  const int kbs = kg << 2;         // 4 k columns (and 4 d columns for PV)
  const int key0 = ((kbs + 0) ^ kg) & 15;
  const int key1 = ((kbs + 1) ^ kg) & 15;
  const int key2 = ((kbs + 2) ^ kg) & 15;
  const int key3 = ((kbs + 3) ^ kg) & 15;

  float sumw = 0.0f;
#pragma unroll
  for (int h = 0; h < 64; ++h) sumw += wv[h];  // uniform -> scalar loads

  {  // Q rows: 8x64 floats = 128 float4, one per thread
    const int r = t >> 4, sl = t & 15;
    *(float4*)&qs[r][sl * 4] =
        *(const float4*)&eqp[(long long)(b * QDIM + q0 + r) * 64 + sl * 4];
  }

  float4 o4 = make_float4(0.0f, 0.0f, 0.0f, 0.0f);
  float m = -3.0e38f, l = 0.0f;

  for (int kt = 0; kt < ntiles; ++kt) {
    __syncthreads();  // prev PV done reading vs/ps
    // stage Ek (swizzled, round-3 writer pattern) + V (linear)
#pragma unroll
    for (int i = 0; i < 8; ++i) {
      const int f = i * 128 + t;
      const int k = f >> 4, sl = f & 15;
      const int key = (k ^ (k >> 2)) & 15;
      const long long grow = (long long)(b * KDIM + kt * 64 + k) * 64 + sl * 4;
      *(float4*)&ks[k][(sl ^ key) * 4] = *(const float4*)&ekp[grow];
      *(float4*)&vs[k][sl * 4] = *(const float4*)&vglob[grow];
    }
    __syncthreads();

    // ---- scores for (tq, kbs..kbs+3): reg double-buffered h-pipeline ----
    float acc0 = 0.0f, acc1 = 0.0f, acc2 = 0.0f, acc3 = 0.0f;
    float4 qA, kA0, kA1, kA2, kA3;
    float4 qB, kB0, kB1, kB2, kB3;

#define LOAD_STAGE(QF, K0, K1, K2, K3, H)                  \
  QF = *(const float4*)&qs[tq][(H) * 4];                   \
  K0 = *(const float4*)&ks[kbs + 0][((H) ^ key0) * 4];     \
  K1 = *(const float4*)&ks[kbs + 1][((H) ^ key1) * 4];     \
  K2 = *(const float4*)&ks[kbs + 2][((H) ^ key2) * 4];     \
  K3 = *(const float4*)&ks[kbs + 3][((H) ^ key3) * 4];

// quad rational: acc += (n01*d23 + n23*d01) * rcp(d01*d23), ui = 1+Eq*Ek
#define QUAD(ACC, QF, KF, W0, W1, W2, W3)                  \
  {                                                        \
    const float u0 = fmaf(QF.x, KF.x, 1.0f);               \
    const float u1 = fmaf(QF.y, KF.y, 1.0f);               \
    const float u2 = fmaf(QF.z, KF.z, 1.0f);               \
    const float u3 = fmaf(QF.w, KF.w, 1.0f);               \
    const float d01 = u0 * u1;                             \
    const float d23 = u2 * u3;                             \
    const float n01 = fmaf(W1, u0, W0 * u1);               \
    const float n23 = fmaf(W3, u2, W2 * u3);               \
    const float num = fmaf(n23, d01, n01 * d23);           \
    ACC = fmaf(num, __builtin_amdgcn_rcpf(d01 * d23), ACC);\
  }

#define COMP_STAGE(QF, K0, K1, K2, K3, H)                  \
  {                                                        \
    const float w0 = wv[(H) * 4 + 0];                      \
    const float w1 = wv[(H) * 4 + 1];                      \
    const float w2 = wv[(H) * 4 + 2];                      \
    const float w3 = wv[(H) * 4 + 3];                      \
    QUAD(acc0, QF, K0, w0, w1, w2, w3)                     \
    QUAD(acc1, QF, K1, w0, w1, w2, w3)                     \
    QUAD(acc2, QF, K2, w0, w1, w2, w3)                     \
    QUAD(acc3, QF, K3, w0, w1, w2, w3)                     \
  }

    LOAD_STAGE(qA, kA0, kA1, kA2, kA3, 0)
#pragma unroll
    for (int h = 0; h < 16; h += 2) {
      LOAD_STAGE(qB, kB0, kB1, kB2, kB3, h + 1)
      COMP_STAGE(qA, kA0, kA1, kA2, kA3, h)
      if (h + 2 < 16) LOAD_STAGE(qA, kA0, kA1, kA2, kA3, h + 2)
      COMP_STAGE(qB, kB0, kB1, kB2, kB3, h + 1)
    }
#undef LOAD_STAGE
#undef COMP_STAGE
#undef QUAD

    // ---- mask + online softmax (row = 16 kg lanes, in-wave) ----
    const int kgl = kt * 64 + kbs;
    float s0 = fmaf(-2.0f, acc0, sumw);
    float s1 = fmaf(-2.0f, acc1, sumw);
    float s2 = fmaf(-2.0f, acc2, sumw);
    float s3 = fmaf(-2.0f, acc3, sumw);
    s0 = (kgl + 0 < vlen) ? s0 : -3.0e38f;
    s1 = (kgl + 1 < vlen) ? s1 : -3.0e38f;
    s2 = (kgl + 2 < vlen) ? s2 : -3.0e38f;
    s3 = (kgl + 3 < vlen) ? s3 : -3.0e38f;
    float tm = fmaxf(fmaxf(s0, s1), fmaxf(s2, s3));
#pragma unroll
    for (int s = 1; s < 16; s <<= 1) tm = fmaxf(tm, __shfl_xor(tm, s, 64));
    const float mn = fmaxf(m, tm);
    const float scale = __builtin_amdgcn_exp2f((m - mn) * kLog2e);
    const float p0 = __builtin_amdgcn_exp2f((s0 - mn) * kLog2e);
    const float p1 = __builtin_amdgcn_exp2f((s1 - mn) * kLog2e);
    const float p2 = __builtin_amdgcn_exp2f((s2 - mn) * kLog2e);
    const float p3 = __builtin_amdgcn_exp2f((s3 - mn) * kLog2e);
    float tsum = (p0 + p1) + (p2 + p3);
#pragma unroll
    for (int s = 1; s < 16; s <<= 1) tsum += __shfl_xor(tsum, s, 64);
    l = fmaf(l, scale, tsum);
    m = mn;
    o4.x *= scale; o4.y *= scale; o4.z *= scale; o4.w *= scale;
    *(float4*)&ps[tq][kbs] = make_float4(p0, p1, p2, p3);
    __syncthreads();

    // ---- PV: o4 += sum_k ps[tq][k] * vs[k][kbs..kbs+3] ----
    // ps read: 16 kg lanes same addr (broadcast); vs read: 16 kg x 4 dwords
    // = 64 dwords over 32 banks (2-way, free); tq groups broadcast.
#pragma unroll 4
    for (int k4 = 0; k4 < 16; ++k4) {
      const float4 p4 = *(const float4*)&ps[tq][k4 * 4];
      const float pw[4] = {p4.x, p4.y, p4.z, p4.w};
#pragma unroll
      for (int e = 0; e < 4; ++e) {
        const float4 vv = *(const float4*)&vs[k4 * 4 + e][kbs];
        o4.x = fmaf(pw[e], vv.x, o4.x);
        o4.y = fmaf(pw[e], vv.y, o4.y);
        o4.z = fmaf(pw[e], vv.z, o4.z);
        o4.w = fmaf(pw[e], vv.w, o4.w);
      }
    }
  }

  const float inv = __builtin_amdgcn_rcpf(l);
  *(float4*)&out[(long long)(b * QDIM + q0 + tq) * 64 + kbs] =
      make_float4(o4.x * inv, o4.y * inv, o4.z * inv, o4.w * inv);
}

// ---------------------------------------------------------------------------
extern "C" void kernel_launch(void* const* d_in, const int* in_sizes, int n_in,
                              void* d_out, int out_size, void* d_ws, size_t ws_size,
                              hipStream_t stream) {
  const float* queries = (const float*)d_in[0];
  const float* keys    = (const float*)d_in[1];
  const float* values  = (const float*)d_in[2];
  const int*   vlens   = (const int*)d_in[3];
  const float* Wq      = (const float*)d_in[4];
  const float* Wk      = (const float*)d_in[5];
  const float* wv      = (const float*)d_in[6];
  float* out = (float*)d_out;

  float* eq = (float*)d_ws;                     // B*Q*H = 2 MB
  float* ek = eq + (size_t)BDIM * QDIM * HDIM;  // B*K*H = 2 MB

  proj_both<<<dim3(256), 256, 0, stream>>>(queries, keys, Wq, Wk, eq, ek);
  fused_kernel<<<dim3(1024), 128, 0, stream>>>(eq, ek, values, wv, vlens, out);
}

// Round 10
// 62.683 us; speedup vs baseline: 1.5530x; 1.1190x over previous
//
#include <hip/hip_runtime.h>

// Problem sizes (fixed by the reference)
#define BDIM 8
#define QDIM 1024
#define KDIM 1024
#define HDIM 64   // = DQ = DK = DV
#define KTPC 2    // k-tiles (64 keys) per chunk -> uniform block cost
#define MAXCH 8   // ceil(16/KTPC)

constexpr float kLog2e = 1.4426950408889634f;
constexpr float kC2 = 2.0f * kLog2e;

// ---------------------------------------------------------------------------
// K1: both projections; emits Eq/Ek = min(exp2(kC2 * (X@W)), 2^15).
// Clamp keeps quad-rational denominators finite; tanh error < 2^-25.
// ---------------------------------------------------------------------------
__global__ __launch_bounds__(256) void proj_both(
    const float* __restrict__ queries, const float* __restrict__ keys,
    const float* __restrict__ Wq, const float* __restrict__ Wk,
    float* __restrict__ eq, float* __restrict__ ek) {
  const int bid = blockIdx.x;
  const bool isK = bid >= 128;
  const float* X = isK ? keys : queries;
  const float* W = isK ? Wk : Wq;
  float* Y = isK ? ek : eq;
  const long long base = (long long)(bid & 127) * 64 * 64;

  __shared__ __align__(16) float xs[64][68];
  __shared__ __align__(16) float ws[64][64];
  const int t = threadIdx.x;
  {
    const int r = t >> 4, sl = t & 15;
#pragma unroll
    for (int i = 0; i < 4; ++i) {
      *(float4*)&xs[r + i * 16][sl * 4] =
          *(const float4*)&X[base + (long long)(r + i * 16) * 64 + sl * 4];
      *(float4*)&ws[r + i * 16][sl * 4] =
          *(const float4*)&W[(r + i * 16) * 64 + sl * 4];
    }
  }
  __syncthreads();

  const int r = t >> 2;
  const int c0 = (t & 3) * 16;
  float acc[16];
#pragma unroll
  for (int j = 0; j < 16; ++j) acc[j] = 0.0f;

#pragma unroll 8
  for (int d = 0; d < 64; ++d) {
    const float xv = xs[r][d];
#pragma unroll
    for (int j4 = 0; j4 < 4; ++j4) {
      float4 w4 = *(float4*)&ws[d][c0 + j4 * 4];
      acc[j4 * 4 + 0] = fmaf(xv, w4.x, acc[j4 * 4 + 0]);
      acc[j4 * 4 + 1] = fmaf(xv, w4.y, acc[j4 * 4 + 1]);
      acc[j4 * 4 + 2] = fmaf(xv, w4.z, acc[j4 * 4 + 2]);
      acc[j4 * 4 + 3] = fmaf(xv, w4.w, acc[j4 * 4 + 3]);
    }
  }
#pragma unroll
  for (int j4 = 0; j4 < 4; ++j4) {
    float4 o = make_float4(
        fminf(__builtin_amdgcn_exp2f(acc[j4 * 4 + 0] * kC2), 32768.0f),
        fminf(__builtin_amdgcn_exp2f(acc[j4 * 4 + 1] * kC2), 32768.0f),
        fminf(__builtin_amdgcn_exp2f(acc[j4 * 4 + 2] * kC2), 32768.0f),
        fminf(__builtin_amdgcn_exp2f(acc[j4 * 4 + 3] * kC2), 32768.0f));
    *(float4*)&Y[base + (long long)r * 64 + c0 + j4 * 4] = o;
  }
}

// ---------------------------------------------------------------------------
// K2: fused scores + online softmax + PV over ONE chunk (<=2 k-tiles).
// Block = 16 q-rows x 256 thr (tq=t>>4, kg=t&15): proven conflict-free
// swizzle pattern, 4 quad-rational chains/thread. Worklist item =
// (b, chunk, qtile16), chunk-outer / q-inner so co-dispatched blocks share
// Ek/V tiles in L2. ~2200 uniform-cost blocks -> backfill keeps 12 waves/CU
// until the tail (fixes round-9's 13% decaying occupancy).
// Emits per-chunk partials (m, l, o[16][64]); combine merges <=8 chunks.
// ---------------------------------------------------------------------------
__global__ __launch_bounds__(256, 3) void fused_kernel(
    const float* __restrict__ eqp, const float* __restrict__ ekp,
    const float* __restrict__ vglob, const float* __restrict__ wv,
    const int* __restrict__ vlens, float* __restrict__ part_o,
    float2* __restrict__ part_ml) {
  // ---- uniform worklist mapping (scalar) ----
  int pre[9];
  pre[0] = 0;
#pragma unroll
  for (int bb = 0; bb < 8; ++bb) {
    int nt = (vlens[bb] + 63) >> 6;
    nt = nt < 16 ? nt : 16;
    const int nch = (nt + KTPC - 1) / KTPC;
    pre[bb + 1] = pre[bb] + (nch << 6);  // nch chunks x 64 q-tiles
  }
  const int g = blockIdx.x;
  if (g >= pre[8]) return;
  int b = 0;
#pragma unroll
  for (int i = 0; i < 7; ++i) b += (g >= pre[i + 1]);
  const int local = g - pre[b];
  const int qt = local & 63;   // q-tile fastest (adjacent blocks share chunk)
  const int ch = local >> 6;
  const int q0 = qt * 16;
  const int vlen = vlens[b];
  int nt = (vlen + 63) >> 6;
  nt = nt < 16 ? nt : 16;
  const int kt0 = ch * KTPC;
  const int ktend = (kt0 + KTPC < nt) ? kt0 + KTPC : nt;

  __shared__ __align__(16) float qs[16][64];  // broadcast reads, no pad needed
  __shared__ __align__(16) float ks[64][64];  // XOR-swizzled Ek tile
  __shared__ __align__(16) float vs[64][64];  // V tile (linear)
  __shared__ __align__(16) float ps[16][68];  // attn weights
  const int t = threadIdx.x;
  const int tq = t >> 4;           // q row 0..15
  const int kg = t & 15;           // k group / d group
  const int kbs = kg << 2;
  const int key0 = ((kbs + 0) ^ kg) & 15;
  const int key1 = ((kbs + 1) ^ kg) & 15;
  const int key2 = ((kbs + 2) ^ kg) & 15;
  const int key3 = ((kbs + 3) ^ kg) & 15;

  float sumw = 0.0f;
#pragma unroll
  for (int h = 0; h < 64; ++h) sumw += wv[h];  // uniform -> scalar loads

  {  // Q rows: 16x64 floats = 256 float4, one per thread
    const int r = t >> 4, sl = t & 15;
    *(float4*)&qs[r][sl * 4] =
        *(const float4*)&eqp[(long long)(b * QDIM + q0 + r) * 64 + sl * 4];
  }

  float4 o4 = make_float4(0.0f, 0.0f, 0.0f, 0.0f);
  float m = -3.0e38f, l = 0.0f;

  for (int kt = kt0; kt < ktend; ++kt) {
    __syncthreads();  // prev PV done reading vs/ps
    // stage Ek (swizzled) + V (linear): 4 float4 each per thread
#pragma unroll
    for (int i = 0; i < 4; ++i) {
      const int f = i * 256 + t;
      const int k = f >> 4, sl = f & 15;
      const int key = (k ^ (k >> 2)) & 15;
      const long long grow = (long long)(b * KDIM + kt * 64 + k) * 64 + sl * 4;
      *(float4*)&ks[k][(sl ^ key) * 4] = *(const float4*)&ekp[grow];
      *(float4*)&vs[k][sl * 4] = *(const float4*)&vglob[grow];
    }
    __syncthreads();

    // ---- scores for (tq, kbs..kbs+3): reg double-buffered h-pipeline ----
    float acc0 = 0.0f, acc1 = 0.0f, acc2 = 0.0f, acc3 = 0.0f;
    float4 qA, kA0, kA1, kA2, kA3;
    float4 qB, kB0, kB1, kB2, kB3;

#define LOAD_STAGE(QF, K0, K1, K2, K3, H)                  \
  QF = *(const float4*)&qs[tq][(H) * 4];                   \
  K0 = *(const float4*)&ks[kbs + 0][((H) ^ key0) * 4];     \
  K1 = *(const float4*)&ks[kbs + 1][((H) ^ key1) * 4];     \
  K2 = *(const float4*)&ks[kbs + 2][((H) ^ key2) * 4];     \
  K3 = *(const float4*)&ks[kbs + 3][((H) ^ key3) * 4];

// quad rational: acc += (n01*d23 + n23*d01) * rcp(d01*d23), ui = 1+Eq*Ek
#define QUAD(ACC, QF, KF, W0, W1, W2, W3)                  \
  {                                                        \
    const float u0 = fmaf(QF.x, KF.x, 1.0f);               \
    const float u1 = fmaf(QF.y, KF.y, 1.0f);               \
    const float u2 = fmaf(QF.z, KF.z, 1.0f);               \
    const float u3 = fmaf(QF.w, KF.w, 1.0f);               \
    const float d01 = u0 * u1;                             \
    const float d23 = u2 * u3;                             \
    const float n01 = fmaf(W1, u0, W0 * u1);               \
    const float n23 = fmaf(W3, u2, W2 * u3);               \
    const float num = fmaf(n23, d01, n01 * d23);           \
    ACC = fmaf(num, __builtin_amdgcn_rcpf(d01 * d23), ACC);\
  }

#define COMP_STAGE(QF, K0, K1, K2, K3, H)                  \
  {                                                        \
    const float w0 = wv[(H) * 4 + 0];                      \
    const float w1 = wv[(H) * 4 + 1];                      \
    const float w2 = wv[(H) * 4 + 2];                      \
    const float w3 = wv[(H) * 4 + 3];                      \
    QUAD(acc0, QF, K0, w0, w1, w2, w3)                     \
    QUAD(acc1, QF, K1, w0, w1, w2, w3)                     \
    QUAD(acc2, QF, K2, w0, w1, w2, w3)                     \
    QUAD(acc3, QF, K3, w0, w1, w2, w3)                     \
  }

    LOAD_STAGE(qA, kA0, kA1, kA2, kA3, 0)
#pragma unroll
    for (int h = 0; h < 16; h += 2) {
      LOAD_STAGE(qB, kB0, kB1, kB2, kB3, h + 1)
      COMP_STAGE(qA, kA0, kA1, kA2, kA3, h)
      if (h + 2 < 16) LOAD_STAGE(qA, kA0, kA1, kA2, kA3, h + 2)
      COMP_STAGE(qB, kB0, kB1, kB2, kB3, h + 1)
    }
#undef LOAD_STAGE
#undef COMP_STAGE
#undef QUAD

    // ---- mask + online softmax (row = 16 kg lanes, in-wave) ----
    const int kgl = kt * 64 + kbs;
    float s0 = fmaf(-2.0f, acc0, sumw);
    float s1 = fmaf(-2.0f, acc1, sumw);
    float s2 = fmaf(-2.0f, acc2, sumw);
    float s3 = fmaf(-2.0f, acc3, sumw);
    s0 = (kgl + 0 < vlen) ? s0 : -3.0e38f;
    s1 = (kgl + 1 < vlen) ? s1 : -3.0e38f;
    s2 = (kgl + 2 < vlen) ? s2 : -3.0e38f;
    s3 = (kgl + 3 < vlen) ? s3 : -3.0e38f;
    float tm = fmaxf(fmaxf(s0, s1), fmaxf(s2, s3));
#pragma unroll
    for (int s = 1; s < 16; s <<= 1) tm = fmaxf(tm, __shfl_xor(tm, s, 64));
    const float mn = fmaxf(m, tm);
    const float scale = __builtin_amdgcn_exp2f((m - mn) * kLog2e);
    const float p0 = __builtin_amdgcn_exp2f((s0 - mn) * kLog2e);
    const float p1 = __builtin_amdgcn_exp2f((s1 - mn) * kLog2e);
    const float p2 = __builtin_amdgcn_exp2f((s2 - mn) * kLog2e);
    const float p3 = __builtin_amdgcn_exp2f((s3 - mn) * kLog2e);
    float tsum = (p0 + p1) + (p2 + p3);
#pragma unroll
    for (int s = 1; s < 16; s <<= 1) tsum += __shfl_xor(tsum, s, 64);
    l = fmaf(l, scale, tsum);
    m = mn;
    o4.x *= scale; o4.y *= scale; o4.z *= scale; o4.w *= scale;
    *(float4*)&ps[tq][kbs] = make_float4(p0, p1, p2, p3);
    __syncthreads();

    // ---- PV: o4 += sum_k ps[tq][k] * vs[k][kbs..kbs+3] ----
#pragma unroll 4
    for (int k4 = 0; k4 < 16; ++k4) {
      const float4 p4 = *(const float4*)&ps[tq][k4 * 4];
      const float pw[4] = {p4.x, p4.y, p4.z, p4.w};
#pragma unroll
      for (int e = 0; e < 4; ++e) {
        const float4 vv = *(const float4*)&vs[k4 * 4 + e][kbs];
        o4.x = fmaf(pw[e], vv.x, o4.x);
        o4.y = fmaf(pw[e], vv.y, o4.y);
        o4.z = fmaf(pw[e], vv.z, o4.z);
        o4.w = fmaf(pw[e], vv.w, o4.w);
      }
    }
  }

  // ---- write chunk partials (slot = g) ----
  *(float4*)&part_o[((long long)g * 16 + tq) * 64 + kbs] = o4;
  if (kg == 0) part_ml[g * 16 + tq] = make_float2(m, l);
}

// ---------------------------------------------------------------------------
// K3: combine <=MAXCH chunk partials per q-row. 256 thr = 4 rows x 64 lanes.
// out[row][d] = sum_c w_c*o_c[d] / sum_c w_c*l_c, w_c = e^{m_c - M}.
// ---------------------------------------------------------------------------
__global__ __launch_bounds__(256) void combine_kernel(
    const float* __restrict__ part_o, const float2* __restrict__ part_ml,
    const int* __restrict__ vlens, float* __restrict__ out) {
  int pre[8], nchv[8];
  int run = 0;
#pragma unroll
  for (int bb = 0; bb < 8; ++bb) {
    int nt = (vlens[bb] + 63) >> 6;
    nt = nt < 16 ? nt : 16;
    nchv[bb] = (nt + KTPC - 1) / KTPC;
    pre[bb] = run;
    run += nchv[bb] << 6;
  }
  const int t = threadIdx.x;
  const int row = blockIdx.x * 4 + (t >> 6);
  const int lane = t & 63;
  const int b = row >> 10;
  const int q = row & (QDIM - 1);
  const int qt = q >> 4;
  const int tq = q & 15;
  const int nch = nchv[b];
  const int slot0 = pre[b] + qt;  // slot for chunk c = slot0 + c*64

  float M = -3.0e38f;
  float mv[MAXCH], lv[MAXCH];
#pragma unroll
  for (int c = 0; c < MAXCH; ++c) {
    if (c < nch) {
      const float2 ml = part_ml[(slot0 + (c << 6)) * 16 + tq];
      mv[c] = ml.x;
      lv[c] = ml.y;
      M = fmaxf(M, ml.x);
    }
  }
  float L = 0.0f, acc = 0.0f;
#pragma unroll
  for (int c = 0; c < MAXCH; ++c) {
    if (c < nch) {
      const float w = __builtin_amdgcn_exp2f((mv[c] - M) * kLog2e);
      L = fmaf(lv[c], w, L);
      const float ov =
          part_o[((long long)(slot0 + (c << 6)) * 16 + tq) * 64 + lane];
      acc = fmaf(ov, w, acc);
    }
  }
  out[(long long)row * 64 + lane] = acc * __builtin_amdgcn_rcpf(L);
}

// ---------------------------------------------------------------------------
extern "C" void kernel_launch(void* const* d_in, const int* in_sizes, int n_in,
                              void* d_out, int out_size, void* d_ws, size_t ws_size,
                              hipStream_t stream) {
  const float* queries = (const float*)d_in[0];
  const float* keys    = (const float*)d_in[1];
  const float* values  = (const float*)d_in[2];
  const int*   vlens   = (const int*)d_in[3];
  const float* Wq      = (const float*)d_in[4];
  const float* Wk      = (const float*)d_in[5];
  const float* wv      = (const float*)d_in[6];
  float* out = (float*)d_out;

  float*  eq      = (float*)d_ws;                      // B*Q*H = 2 MB
  float*  ek      = eq + (size_t)BDIM * QDIM * HDIM;   // B*K*H = 2 MB
  float*  part_o  = ek + (size_t)BDIM * KDIM * HDIM;   // 4096*16*64*4 = 16.8 MB
  float2* part_ml = (float2*)(part_o + (size_t)4096 * 16 * 64);  // 512 KB

  proj_both<<<dim3(256), 256, 0, stream>>>(queries, keys, Wq, Wk, eq, ek);
  // max worklist = 8 b * 8 chunks * 64 q-tiles = 4096; invalid tail exits.
  fused_kernel<<<dim3(4096), 256, 0, stream>>>(eq, ek, values, wv, vlens,
                                               part_o, part_ml);
  combine_kernel<<<dim3(BDIM * QDIM / 4), 256, 0, stream>>>(part_o, part_ml,
                                                            vlens, out);
}

// Round 11
// 54.851 us; speedup vs baseline: 1.7747x; 1.1428x over previous
//
#include <hip/hip_runtime.h>

// Problem sizes (fixed by the reference)
#define BDIM 8
#define QDIM 1024
#define KDIM 1024
#define HDIM 64   // = DQ = DK = DV
#define KTPC 2    // k-tiles (64 keys) per chunk -> uniform block cost
#define MAXCH 8   // ceil(16/KTPC)

constexpr float kLog2e = 1.4426950408889634f;
constexpr float kC2 = 2.0f * kLog2e;

// ---------------------------------------------------------------------------
// K1: both projections; emits Eq/Ek = min(exp2(kC2 * (X@W)), 2^15).
// 512 blocks x 32 rows (2+ blocks/CU; round-10's 256x64 ran 1 block/CU,
// latency-bound at 4.5us for ~0.9us of math).
// ---------------------------------------------------------------------------
__global__ __launch_bounds__(256) void proj_both(
    const float* __restrict__ queries, const float* __restrict__ keys,
    const float* __restrict__ Wq, const float* __restrict__ Wk,
    float* __restrict__ eq, float* __restrict__ ek) {
  const int bid = blockIdx.x;
  const bool isK = bid >= 256;
  const float* X = isK ? keys : queries;
  const float* W = isK ? Wk : Wq;
  float* Y = isK ? ek : eq;
  const long long base = (long long)(bid & 255) * 32 * 64;

  __shared__ __align__(16) float xs[32][68];
  __shared__ __align__(16) float ws[64][64];
  const int t = threadIdx.x;
  {
    const int r = t >> 4, sl = t & 15;
#pragma unroll
    for (int i = 0; i < 2; ++i)
      *(float4*)&xs[r + i * 16][sl * 4] =
          *(const float4*)&X[base + (long long)(r + i * 16) * 64 + sl * 4];
#pragma unroll
    for (int i = 0; i < 4; ++i)
      *(float4*)&ws[r + i * 16][sl * 4] =
          *(const float4*)&W[(r + i * 16) * 64 + sl * 4];
  }
  __syncthreads();

  const int r = t >> 3;            // 0..31
  const int c0 = (t & 7) * 8;      // 8 output cols per thread
  float acc[8];
#pragma unroll
  for (int j = 0; j < 8; ++j) acc[j] = 0.0f;

#pragma unroll 8
  for (int d = 0; d < 64; ++d) {
    const float xv = xs[r][d];
#pragma unroll
    for (int j4 = 0; j4 < 2; ++j4) {
      float4 w4 = *(float4*)&ws[d][c0 + j4 * 4];
      acc[j4 * 4 + 0] = fmaf(xv, w4.x, acc[j4 * 4 + 0]);
      acc[j4 * 4 + 1] = fmaf(xv, w4.y, acc[j4 * 4 + 1]);
      acc[j4 * 4 + 2] = fmaf(xv, w4.z, acc[j4 * 4 + 2]);
      acc[j4 * 4 + 3] = fmaf(xv, w4.w, acc[j4 * 4 + 3]);
    }
  }
#pragma unroll
  for (int j4 = 0; j4 < 2; ++j4) {
    float4 o = make_float4(
        fminf(__builtin_amdgcn_exp2f(acc[j4 * 4 + 0] * kC2), 32768.0f),
        fminf(__builtin_amdgcn_exp2f(acc[j4 * 4 + 1] * kC2), 32768.0f),
        fminf(__builtin_amdgcn_exp2f(acc[j4 * 4 + 2] * kC2), 32768.0f),
        fminf(__builtin_amdgcn_exp2f(acc[j4 * 4 + 3] * kC2), 32768.0f));
    *(float4*)&Y[base + (long long)r * 64 + c0 + j4 * 4] = o;
  }
}

// ---------------------------------------------------------------------------
// K2: fused scores + softmax-numerator + PV over one chunk (<=2 k-tiles).
// NO online max: |score| <= sumabs = sum|wv| (uniform bound), so
// p = exp2((s - sumabs)*log2e) in (0,1] can never overflow. This removes
// both per-tile shuffle reductions, the o-rescale, and the serial m-chain.
// l accumulates per-thread, reduced once per chunk.
// LDS = exactly 40KB -> 4 blocks/CU (16 waves/CU). ps is unpadded but
// column-rotated by tq (read banks distinct across the 4 wave rows);
// ps produce/consume is wave-internal -> no barrier needed for it.
// ---------------------------------------------------------------------------
__global__ __launch_bounds__(256, 4) void fused_kernel(
    const float* __restrict__ eqp, const float* __restrict__ ekp,
    const float* __restrict__ vglob, const float* __restrict__ wv,
    const int* __restrict__ vlens, float* __restrict__ part_o,
    float* __restrict__ part_l) {
  // ---- uniform worklist mapping (scalar) ----
  int pre[9];
  pre[0] = 0;
#pragma unroll
  for (int bb = 0; bb < 8; ++bb) {
    int nt = (vlens[bb] + 63) >> 6;
    nt = nt < 16 ? nt : 16;
    const int nch = (nt + KTPC - 1) / KTPC;
    pre[bb + 1] = pre[bb] + (nch << 6);  // nch chunks x 64 q-tiles
  }
  const int g = blockIdx.x;
  if (g >= pre[8]) return;
  int b = 0;
#pragma unroll
  for (int i = 0; i < 7; ++i) b += (g >= pre[i + 1]);
  const int local = g - pre[b];
  const int qt = local & 63;   // q-tile fastest (adjacent blocks share chunk)
  const int ch = local >> 6;
  const int q0 = qt * 16;
  const int vlen = vlens[b];
  int nt = (vlen + 63) >> 6;
  nt = nt < 16 ? nt : 16;
  const int kt0 = ch * KTPC;
  const int ktend = (kt0 + KTPC < nt) ? kt0 + KTPC : nt;

  __shared__ __align__(16) float qs[16][64];  // 4 KB (broadcast reads)
  __shared__ __align__(16) float ks[64][64];  // 16 KB XOR-swizzled Ek
  __shared__ __align__(16) float vs[64][64];  // 16 KB V (linear)
  __shared__ __align__(16) float ps[16][64];  // 4 KB, column-rotated by tq
  const int t = threadIdx.x;
  const int tq = t >> 4;           // q row 0..15
  const int kg = t & 15;           // k group / d group
  const int kbs = kg << 2;
  const int key0 = ((kbs + 0) ^ kg) & 15;
  const int key1 = ((kbs + 1) ^ kg) & 15;
  const int key2 = ((kbs + 2) ^ kg) & 15;
  const int key3 = ((kbs + 3) ^ kg) & 15;

  float sumw = 0.0f, sumabs = 0.0f;
#pragma unroll
  for (int h = 0; h < 64; ++h) {   // uniform -> scalar loads
    const float w = wv[h];
    sumw += w;
    sumabs += fabsf(w);
  }
  const float sbias = sumw - sumabs;  // s' = -2*acc + sbias <= 0 always

  {  // Q rows: 16x64 floats = 256 float4, one per thread
    const int r = t >> 4, sl = t & 15;
    *(float4*)&qs[r][sl * 4] =
        *(const float4*)&eqp[(long long)(b * QDIM + q0 + r) * 64 + sl * 4];
  }

  float4 o4 = make_float4(0.0f, 0.0f, 0.0f, 0.0f);
  float l = 0.0f;

  for (int kt = kt0; kt < ktend; ++kt) {
    __syncthreads();  // prev PV done reading vs/ps
    // stage Ek (swizzled) + V (linear): 4 float4 each per thread
#pragma unroll
    for (int i = 0; i < 4; ++i) {
      const int f = i * 256 + t;
      const int k = f >> 4, sl = f & 15;
      const int key = (k ^ (k >> 2)) & 15;
      const long long grow = (long long)(b * KDIM + kt * 64 + k) * 64 + sl * 4;
      *(float4*)&ks[k][(sl ^ key) * 4] = *(const float4*)&ekp[grow];
      *(float4*)&vs[k][sl * 4] = *(const float4*)&vglob[grow];
    }
    __syncthreads();

    // ---- scores for (tq, kbs..kbs+3): reg double-buffered h-pipeline ----
    float acc0 = 0.0f, acc1 = 0.0f, acc2 = 0.0f, acc3 = 0.0f;
    float4 qA, kA0, kA1, kA2, kA3;
    float4 qB, kB0, kB1, kB2, kB3;

#define LOAD_STAGE(QF, K0, K1, K2, K3, H)                  \
  QF = *(const float4*)&qs[tq][(H) * 4];                   \
  K0 = *(const float4*)&ks[kbs + 0][((H) ^ key0) * 4];     \
  K1 = *(const float4*)&ks[kbs + 1][((H) ^ key1) * 4];     \
  K2 = *(const float4*)&ks[kbs + 2][((H) ^ key2) * 4];     \
  K3 = *(const float4*)&ks[kbs + 3][((H) ^ key3) * 4];

// quad rational: acc += (n01*d23 + n23*d01) * rcp(d01*d23), ui = 1+Eq*Ek
#define QUAD(ACC, QF, KF, W0, W1, W2, W3)                  \
  {                                                        \
    const float u0 = fmaf(QF.x, KF.x, 1.0f);               \
    const float u1 = fmaf(QF.y, KF.y, 1.0f);               \
    const float u2 = fmaf(QF.z, KF.z, 1.0f);               \
    const float u3 = fmaf(QF.w, KF.w, 1.0f);               \
    const float d01 = u0 * u1;                             \
    const float d23 = u2 * u3;                             \
    const float n01 = fmaf(W1, u0, W0 * u1);               \
    const float n23 = fmaf(W3, u2, W2 * u3);               \
    const float num = fmaf(n23, d01, n01 * d23);           \
    ACC = fmaf(num, __builtin_amdgcn_rcpf(d01 * d23), ACC);\
  }

#define COMP_STAGE(QF, K0, K1, K2, K3, H)                  \
  {                                                        \
    const float w0 = wv[(H) * 4 + 0];                      \
    const float w1 = wv[(H) * 4 + 1];                      \
    const float w2 = wv[(H) * 4 + 2];                      \
    const float w3 = wv[(H) * 4 + 3];                      \
    QUAD(acc0, QF, K0, w0, w1, w2, w3)                     \
    QUAD(acc1, QF, K1, w0, w1, w2, w3)                     \
    QUAD(acc2, QF, K2, w0, w1, w2, w3)                     \
    QUAD(acc3, QF, K3, w0, w1, w2, w3)                     \
  }

    LOAD_STAGE(qA, kA0, kA1, kA2, kA3, 0)
#pragma unroll
    for (int h = 0; h < 16; h += 2) {
      LOAD_STAGE(qB, kB0, kB1, kB2, kB3, h + 1)
      COMP_STAGE(qA, kA0, kA1, kA2, kA3, h)
      if (h + 2 < 16) LOAD_STAGE(qA, kA0, kA1, kA2, kA3, h + 2)
      COMP_STAGE(qB, kB0, kB1, kB2, kB3, h + 1)
    }
#undef LOAD_STAGE
#undef COMP_STAGE
#undef QUAD

    // ---- p = exp2(s - sumabs): masked lanes -> exact 0; no reductions ----
    const int kgl = kt * 64 + kbs;
    float s0 = fmaf(-2.0f, acc0, sbias);
    float s1 = fmaf(-2.0f, acc1, sbias);
    float s2 = fmaf(-2.0f, acc2, sbias);
    float s3 = fmaf(-2.0f, acc3, sbias);
    s0 = (kgl + 0 < vlen) ? s0 : -3.0e38f;
    s1 = (kgl + 1 < vlen) ? s1 : -3.0e38f;
    s2 = (kgl + 2 < vlen) ? s2 : -3.0e38f;
    s3 = (kgl + 3 < vlen) ? s3 : -3.0e38f;
    const float p0 = __builtin_amdgcn_exp2f(s0 * kLog2e);
    const float p1 = __builtin_amdgcn_exp2f(s1 * kLog2e);
    const float p2 = __builtin_amdgcn_exp2f(s2 * kLog2e);
    const float p3 = __builtin_amdgcn_exp2f(s3 * kLog2e);
    l += (p0 + p1) + (p2 + p3);
    // rotated store: column group (kg+tq)&15 holds k-group kg for row tq
    *(float4*)&ps[tq][(((kg + tq) & 15)) * 4] = make_float4(p0, p1, p2, p3);
    // wave-internal produce/consume (row's 16 lanes are in one wave):
    // no barrier; lgkmcnt ordering suffices.

    // ---- PV: o4 += sum_k p[k] * vs[k][kbs..kbs+3] ----
#pragma unroll 4
    for (int k4 = 0; k4 < 16; ++k4) {
      const int kk = (k4 + tq) & 15;  // read col (kk+tq)&15 holds group kk
      const float4 p4 = *(const float4*)&ps[tq][((kk + tq) & 15) * 4];
      const float pw[4] = {p4.x, p4.y, p4.z, p4.w};
#pragma unroll
      for (int e = 0; e < 4; ++e) {
        const float4 vv = *(const float4*)&vs[kk * 4 + e][kbs];
        o4.x = fmaf(pw[e], vv.x, o4.x);
        o4.y = fmaf(pw[e], vv.y, o4.y);
        o4.z = fmaf(pw[e], vv.z, o4.z);
        o4.w = fmaf(pw[e], vv.w, o4.w);
      }
    }
  }

  // ---- reduce l over the 16 kg lanes (in-wave), write chunk partials ----
#pragma unroll
  for (int s = 1; s < 16; s <<= 1) l += __shfl_xor(l, s, 64);
  *(float4*)&part_o[((long long)g * 16 + tq) * 64 + kbs] = o4;
  if (kg == 0) part_l[g * 16 + tq] = l;
}

// ---------------------------------------------------------------------------
// K3: combine <=MAXCH chunk partials per q-row: plain sums (common shift
// cancels). 256 thr = 4 rows x 64 lanes.
// ---------------------------------------------------------------------------
__global__ __launch_bounds__(256) void combine_kernel(
    const float* __restrict__ part_o, const float* __restrict__ part_l,
    const int* __restrict__ vlens, float* __restrict__ out) {
  int pre[8], nchv[8];
  int run = 0;
#pragma unroll
  for (int bb = 0; bb < 8; ++bb) {
    int nt = (vlens[bb] + 63) >> 6;
    nt = nt < 16 ? nt : 16;
    nchv[bb] = (nt + KTPC - 1) / KTPC;
    pre[bb] = run;
    run += nchv[bb] << 6;
  }
  const int t = threadIdx.x;
  const int row = blockIdx.x * 4 + (t >> 6);
  const int lane = t & 63;
  const int b = row >> 10;
  const int q = row & (QDIM - 1);
  const int qt = q >> 4;
  const int tq = q & 15;
  const int nch = nchv[b];
  const int slot0 = pre[b] + qt;  // slot for chunk c = slot0 + c*64

  float L = 0.0f, acc = 0.0f;
#pragma unroll
  for (int c = 0; c < MAXCH; ++c) {
    if (c < nch) {
      L += part_l[(slot0 + (c << 6)) * 16 + tq];
      acc += part_o[((long long)(slot0 + (c << 6)) * 16 + tq) * 64 + lane];
    }
  }
  out[(long long)row * 64 + lane] = acc * __builtin_amdgcn_rcpf(L);
}

// ---------------------------------------------------------------------------
extern "C" void kernel_launch(void* const* d_in, const int* in_sizes, int n_in,
                              void* d_out, int out_size, void* d_ws, size_t ws_size,
                              hipStream_t stream) {
  const float* queries = (const float*)d_in[0];
  const float* keys    = (const float*)d_in[1];
  const float* values  = (const float*)d_in[2];
  const int*   vlens   = (const int*)d_in[3];
  const float* Wq      = (const float*)d_in[4];
  const float* Wk      = (const float*)d_in[5];
  const float* wv      = (const float*)d_in[6];
  float* out = (float*)d_out;

  float* eq     = (float*)d_ws;                      // B*Q*H = 2 MB
  float* ek     = eq + (size_t)BDIM * QDIM * HDIM;   // B*K*H = 2 MB
  float* part_o = ek + (size_t)BDIM * KDIM * HDIM;   // 4096*16*64*4 = 16.8 MB
  float* part_l = part_o + (size_t)4096 * 16 * 64;   // 256 KB

  proj_both<<<dim3(512), 256, 0, stream>>>(queries, keys, Wq, Wk, eq, ek);
  // max worklist = 8 b * 8 chunks * 64 q-tiles = 4096; invalid tail exits.
  fused_kernel<<<dim3(4096), 256, 0, stream>>>(eq, ek, values, wv, vlens,
                                               part_o, part_l);
  combine_kernel<<<dim3(BDIM * QDIM / 4), 256, 0, stream>>>(part_o, part_l,
                                                            vlens, out);
}